// Round 5
// baseline (257.062 us; speedup 1.0000x reference)
//
#include <hip/hip_runtime.h>
#include <cstdint>
#include <cstddef>

#define EPS 1e-8f

// Fixed problem instance
#define Bsz 8
#define Nn  5
#define Kk  5
#define Ll  128
#define Ff  768
#define Tt  11                 // 2N+1
#define KL  640                // K*L
#define ROWS_PER_B 2560        // N*Q*L
#define NROWS 20480
#define F4  192                // Ff/4
#define BN  40                 // B*N

// ---- stage1 geometry ----
#define S1_ROWS 16
#define S1_CH   (KL / S1_ROWS)     // 40 chunks per bn
#define S1_NBLK (BN * S1_CH)       // 1600 blocks
#define PART_STRIDE (3 * Ff)       // 2304 floats per partial record [B|I|O]
#define PART_STRIDE4 (PART_STRIDE / 4)

typedef float v2f __attribute__((ext_vector_type(2)));

// ---------------- Stage 1: masked partial sums ----------------
// 1600 blocks x 192 threads. Lane owns one float4 column; loops 16 rows.
// Masks are 0/1 and BLOCK-UNIFORM per row -> scalar loads + scalar branches;
// accumulate with packed-f32 adds only when the mask fires (avg 3 VALU/float4
// instead of 12 fmaf). O-mask = 1-mb-mi in {-1,0,1} -> add/sub/skip.
__global__ __launch_bounds__(192) void stage1(
    const float* __restrict__ sup,      // [B][N][K][L][F]
    const int*   __restrict__ Bm,       // [B][N][K][L]
    const int*   __restrict__ Im,
    float* __restrict__ part,           // [S1_NBLK][3][Ff]
    float* __restrict__ pcnt)           // [S1_NBLK][2]
{
    int blk = blockIdx.x;
    int bn  = blk / S1_CH;
    int ch  = blk - bn * S1_CH;
    int tid = threadIdx.x;

    const float4* sp = (const float4*)(sup + ((size_t)bn * KL + ch * S1_ROWS) * Ff) + tid;
    const int*    bp = Bm + bn * KL + ch * S1_ROWS;   // block-uniform -> s_load
    const int*    ip = Im + bn * KL + ch * S1_ROWS;

    v2f tB0 = {0.f,0.f}, tB1 = tB0, tI0 = tB0, tI1 = tB0, tO0 = tB0, tO1 = tB0;
    int cB = 0, cI = 0;

    #pragma unroll 4
    for (int p = 0; p < S1_ROWS; ++p) {
        float4 v = sp[p * F4];
        v2f lo = {v.x, v.y};
        v2f hi = {v.z, v.w};
        int mb = bp[p];
        int mi = ip[p];
        if (mb) { tB0 += lo; tB1 += hi; ++cB; }
        if (mi) { tI0 += lo; tI1 += hi; ++cI; }
        int d = 1 - mb - mi;
        if (d == 1)       { tO0 += lo; tO1 += hi; }
        else if (d == -1) { tO0 -= lo; tO1 -= hi; }
    }

    float4* o = (float4*)(part + (size_t)blk * PART_STRIDE);
    float4 rB = {tB0.x, tB0.y, tB1.x, tB1.y};
    float4 rI = {tI0.x, tI0.y, tI1.x, tI1.y};
    float4 rO = {tO0.x, tO0.y, tO1.x, tO1.y};
    o[tid]          = rB;
    o[F4 + tid]     = rI;
    o[2 * F4 + tid] = rO;

    if (tid == 0) {
        pcnt[2 * (size_t)blk]     = (float)cB;
        pcnt[2 * (size_t)blk + 1] = (float)cI;
    }
}

// ---------------- Stage 2: reduce partials -> prototypes ----------------
// 66 blocks x 256 threads. Threads [0,15360): (bn, set in {B,I}, f4).
// Threads [15360,16896): (b, f4) for the O prototype. Thread 0 zeroes loss.
__global__ __launch_bounds__(256) void stage2(
    const float* __restrict__ part,
    const float* __restrict__ pcnt,     // [S1_NBLK][2]
    float* __restrict__ proto,          // [B][Tt][Ff]
    float* __restrict__ loss_out)
{
    int gid = blockIdx.x * 256 + threadIdx.x;
    float4* protoP4 = (float4*)proto;

    if (gid == 0) loss_out[0] = 0.0f;   // visible to stage3 via stream ordering

    if (gid < BN * 2 * F4) {
        int bn  = gid / (2 * F4);
        int r   = gid - bn * 2 * F4;
        int set = r / F4;
        int f4  = r - set * F4;
        const float4* src = (const float4*)(part + (size_t)bn * S1_CH * PART_STRIDE + set * Ff) + f4;
        float4 s = {0,0,0,0};
        float  c = 0.0f;
        #pragma unroll 8
        for (int ch = 0; ch < S1_CH; ++ch) {
            float4 v = src[(size_t)ch * PART_STRIDE4];
            s.x += v.x; s.y += v.y; s.z += v.z; s.w += v.w;
            c += pcnt[2 * (size_t)(bn * S1_CH + ch) + set];
        }
        float sc = 1.0f / (c + EPS);
        int b = bn / Nn, n = bn - b * Nn;
        int tag = 1 + 2 * n + set;
        float4 o = { s.x * sc, s.y * sc, s.z * sc, s.w * sc };
        protoP4[((size_t)b * Tt + tag) * F4 + f4] = o;
    } else if (gid < BN * 2 * F4 + Bsz * F4) {
        int idx = gid - BN * 2 * F4;
        int b   = idx / F4;
        int f4  = idx - b * F4;
        float4 s = {0,0,0,0};
        float cO = (float)(KL * Nn);
        for (int n = 0; n < Nn; ++n) {
            int bn = b * Nn + n;
            const float4* src = (const float4*)(part + (size_t)bn * S1_CH * PART_STRIDE + 2 * Ff) + f4;
            #pragma unroll 8
            for (int ch = 0; ch < S1_CH; ++ch) {
                float4 v = src[(size_t)ch * PART_STRIDE4];
                s.x += v.x; s.y += v.y; s.z += v.z; s.w += v.w;
                cO -= pcnt[2 * (size_t)(bn * S1_CH + ch)] + pcnt[2 * (size_t)(bn * S1_CH + ch) + 1];
            }
        }
        float sc = 1.0f / (cO + EPS);
        float4 o = { s.x * sc, s.y * sc, s.z * sc, s.w * sc };
        protoP4[(size_t)b * Tt * F4 + f4] = o;
    }
}

// ---------------- Stage 3: logits + argmax + log-softmax NLL ----------------
// 320 blocks x 128 threads (2 waves). Block covers 64 rows. Thread = 2 rows x
// quarter-row (48 float4). Lane = 4*p + s: p = row-pair, s = f-slice.
// Proto in LDS, slice-padded; acc[22] in registers; 2-shuffle reduction.
#define S3_ROWS 64
#define S3_NBLK (NROWS / S3_ROWS)          // 320
#define BLKS_PER_B (ROWS_PER_B / S3_ROWS)  // 40

__global__ __launch_bounds__(128) void stage3(
    const float* __restrict__ query,    // [B][2560][Ff]
    const float* __restrict__ proto,    // [B][Tt][Ff]
    const int*   __restrict__ label,    // [NROWS]
    float* __restrict__ out_logits,     // [NROWS][Tt]
    float* __restrict__ out_pred,       // [NROWS]
    float* __restrict__ loss_out)       // [1]
{
    __shared__ float4 ldsP[Tt * 4 * 49];   // 34,496 B

    int blk = blockIdx.x;
    int b   = blk / BLKS_PER_B;

    const float4* pg = (const float4*)(proto + (size_t)b * Tt * Ff);
    for (int idx = threadIdx.x; idx < Tt * F4; idx += 128) {
        int t  = idx / F4;
        int f4 = idx - t * F4;
        int s  = f4 / 48;
        int j  = f4 - 48 * s;
        ldsP[(t * 4 + s) * 49 + j] = pg[idx];
    }
    __syncthreads();

    int w    = threadIdx.x >> 6;
    int lane = threadIdx.x & 63;
    int p    = lane >> 2;
    int s    = lane & 3;

    size_t row0 = (size_t)blk * S3_ROWS + w * 32 + p * 2;
    const float4* q0 = (const float4*)(query + row0 * Ff) + s * 48;
    const float4* q1 = q0 + F4;

    float a0[Tt], a1[Tt];
    #pragma unroll
    for (int t = 0; t < Tt; ++t) { a0[t] = 0.0f; a1[t] = 0.0f; }

    const float4* pb = &ldsP[s * 49];
    #pragma unroll 2
    for (int j = 0; j < 48; ++j) {
        float4 u = q0[j];
        float4 v = q1[j];
        #pragma unroll
        for (int t = 0; t < Tt; ++t) {
            float4 pv = pb[t * (4 * 49) + j];
            float d0 = a0[t], d1 = a1[t];
            d0 = fmaf(u.x, pv.x, d0); d0 = fmaf(u.y, pv.y, d0);
            d0 = fmaf(u.z, pv.z, d0); d0 = fmaf(u.w, pv.w, d0);
            d1 = fmaf(v.x, pv.x, d1); d1 = fmaf(v.y, pv.y, d1);
            d1 = fmaf(v.z, pv.z, d1); d1 = fmaf(v.w, pv.w, d1);
            a0[t] = d0; a1[t] = d1;
        }
    }

    #pragma unroll
    for (int t = 0; t < Tt; ++t) {
        a0[t] += __shfl_xor(a0[t], 1, 64); a0[t] += __shfl_xor(a0[t], 2, 64);
        a1[t] += __shfl_xor(a1[t], 1, 64); a1[t] += __shfl_xor(a1[t], 2, 64);
    }

    float wloss = 0.0f;
    if (s == 0) {
        #pragma unroll
        for (int rr = 0; rr < 2; ++rr) {
            size_t grow = row0 + rr;
            float* a = rr ? a1 : a0;
            float m = a[0]; int bt = 0;
            #pragma unroll
            for (int t = 1; t < Tt; ++t) if (a[t] > m) { m = a[t]; bt = t; }  // first-max
            float sum = 0.0f;
            #pragma unroll
            for (int t = 0; t < Tt; ++t) sum += __expf(a[t] - m);
            int lab = label[grow];
            float labv = a[0];
            #pragma unroll
            for (int t = 1; t < Tt; ++t) labv = (lab == t) ? a[t] : labv;
            #pragma unroll
            for (int t = 0; t < Tt; ++t) out_logits[grow * Tt + t] = a[t];
            out_pred[grow] = (float)bt;
            wloss += (m + __logf(sum)) - labv;
        }
    }
    #pragma unroll
    for (int off = 32; off > 0; off >>= 1) wloss += __shfl_xor(wloss, off, 64);
    if (lane == 0) atomicAdd(loss_out, wloss * (1.0f / (float)NROWS));
}

// ---------------- Host launch ----------------
extern "C" void kernel_launch(void* const* d_in, const int* in_sizes, int n_in,
                              void* d_out, int out_size, void* d_ws, size_t ws_size,
                              hipStream_t stream) {
    const float* sup   = (const float*)d_in[0];
    const float* query = (const float*)d_in[1];
    const int*   Bm    = (const int*)d_in[2];
    const int*   Im    = (const int*)d_in[3];
    const int*   lab   = (const int*)d_in[4];

    // ws layout: part [1600][2304] | pcnt [1600][2] | proto [8][11][768]
    float* w     = (float*)d_ws;
    float* part  = w;
    float* pcnt  = part + (size_t)S1_NBLK * PART_STRIDE;   // +3,686,400
    float* proto = pcnt + 2 * S1_NBLK;                     // +3,200 (16B-aligned)

    float* loss_out   = (float*)d_out;
    float* out_logits = (float*)d_out + 1;
    float* out_pred   = (float*)d_out + 1 + (size_t)NROWS * Tt;

    stage1<<<S1_NBLK, 192, 0, stream>>>(sup, Bm, Im, part, pcnt);
    stage2<<<66, 256, 0, stream>>>(part, pcnt, proto, loss_out);
    stage3<<<S3_NBLK, 128, 0, stream>>>(query, proto, lab, out_logits, out_pred, loss_out);
}

// Round 6
// 201.586 us; speedup vs baseline: 1.2752x; 1.2752x over previous
//
#include <hip/hip_runtime.h>
#include <cstdint>
#include <cstddef>

#define EPS 1e-8f

// Fixed problem instance
#define Bsz 8
#define Nn  5
#define Kk  5
#define Ll  128
#define Ff  768
#define Tt  11                 // 2N+1
#define KL  640                // K*L
#define ROWS_PER_B 2560        // N*Q*L
#define NROWS 20480
#define F4  192                // Ff/4
#define BN  40                 // B*N

// ---- stage1 geometry ----
#define S1_ROWS 16
#define S1_CH   (KL / S1_ROWS)     // 40 chunks per bn
#define S1_NBLK (BN * S1_CH)       // 1600 blocks
#define PART_STRIDE (3 * Ff)       // 2304 floats per record [B|I|All]
#define PART_STRIDE4 (PART_STRIDE / 4)  // 576

typedef float v2f __attribute__((ext_vector_type(2)));

// ---------------- Stage 1: masked partial sums ----------------
// 1600 blocks x 192 threads. Lane owns one float4 column; 16 rows per block.
// Records are {B-sum, I-sum, All-sum}; O is recovered as All-B-I downstream.
// Masks are block-uniform -> scalar loads + uniform branches (no divergence).
// Loads hand-batched 8-deep for ILP.
__global__ __launch_bounds__(192) void stage1(
    const float* __restrict__ sup,      // [B][N][K][L][F]
    const int*   __restrict__ Bm,       // [B][N][K][L]
    const int*   __restrict__ Im,
    float* __restrict__ part,           // [S1_NBLK][3][Ff]
    float* __restrict__ pcnt)           // [S1_NBLK][2]
{
    int blk = blockIdx.x;
    int bn  = blk / S1_CH;
    int ch  = blk - bn * S1_CH;
    int tid = threadIdx.x;

    const float4* sp = (const float4*)(sup + ((size_t)bn * KL + ch * S1_ROWS) * Ff) + tid;
    const int*    bp = Bm + bn * KL + ch * S1_ROWS;   // block-uniform -> s_load
    const int*    ip = Im + bn * KL + ch * S1_ROWS;

    v2f tB0 = {0.f,0.f}, tB1 = tB0, tI0 = tB0, tI1 = tB0, tA0 = tB0, tA1 = tB0;
    int cB = 0, cI = 0;

    #pragma unroll
    for (int h = 0; h < 2; ++h) {
        float4 v[8];
        #pragma unroll
        for (int j = 0; j < 8; ++j) v[j] = sp[(h * 8 + j) * F4];
        #pragma unroll
        for (int j = 0; j < 8; ++j) {
            int p = h * 8 + j;
            v2f lo = {v[j].x, v[j].y};
            v2f hi = {v[j].z, v[j].w};
            tA0 += lo; tA1 += hi;
            if (bp[p]) { tB0 += lo; tB1 += hi; ++cB; }
            if (ip[p]) { tI0 += lo; tI1 += hi; ++cI; }
        }
    }

    float4* o = (float4*)(part + (size_t)blk * PART_STRIDE);
    float4 rB = {tB0.x, tB0.y, tB1.x, tB1.y};
    float4 rI = {tI0.x, tI0.y, tI1.x, tI1.y};
    float4 rA = {tA0.x, tA0.y, tA1.x, tA1.y};
    o[tid]          = rB;
    o[F4 + tid]     = rI;
    o[2 * F4 + tid] = rA;

    if (tid == 0) {
        pcnt[2 * (size_t)blk]     = (float)cB;
        pcnt[2 * (size_t)blk + 1] = (float)cI;
    }
}

// ---------------- Stage 2: reduce 40 chunks -> bnsum ----------------
// 90 blocks x 256 = 23,040 threads = one per (bn, set in {B,I,All}, f4).
// Uniform control flow; loads hand-batched 8-deep (explicit v[8] buffer).
__global__ __launch_bounds__(256) void stage2(
    const float* __restrict__ part,     // [S1_NBLK][3][Ff]
    float* __restrict__ bnsum,          // [BN][3][Ff]
    float* __restrict__ loss_out)
{
    int gid = blockIdx.x * 256 + threadIdx.x;
    if (gid == 0) loss_out[0] = 0.0f;

    int bn  = gid / (3 * F4);
    int r   = gid - bn * (3 * F4);
    int set = r / F4;
    int f4  = r - set * F4;

    const float4* src = (const float4*)(part + (size_t)bn * S1_CH * PART_STRIDE + set * Ff) + f4;
    float4 s = {0, 0, 0, 0};
    #pragma unroll
    for (int c8 = 0; c8 < S1_CH / 8; ++c8) {
        float4 v[8];
        #pragma unroll
        for (int j = 0; j < 8; ++j) v[j] = src[(size_t)(c8 * 8 + j) * PART_STRIDE4];
        #pragma unroll
        for (int j = 0; j < 8; ++j) {
            s.x += v[j].x; s.y += v[j].y; s.z += v[j].z; s.w += v[j].w;
        }
    }
    ((float4*)bnsum)[((size_t)bn * 3 + set) * F4 + f4] = s;
}

// ---------------- Stage 3: normalize + logits + argmax + NLL ----------------
// 320 blocks x 128 threads (2 waves). Block covers 64 rows. Thread = 2 rows x
// quarter-row. Scales computed per-block from pcnt (coalesced + LDS atomics);
// prototypes built into slice-padded LDS from bnsum; acc[22] in registers.
#define S3_ROWS 64
#define S3_NBLK (NROWS / S3_ROWS)          // 320
#define BLKS_PER_B (ROWS_PER_B / S3_ROWS)  // 40

__global__ __launch_bounds__(128) void stage3(
    const float* __restrict__ query,    // [B][2560][Ff]
    const float* __restrict__ bnsum,    // [BN][3][Ff]
    const float* __restrict__ pcnt,     // [S1_NBLK][2]
    const int*   __restrict__ label,    // [NROWS]
    float* __restrict__ out_logits,     // [NROWS][Tt]
    float* __restrict__ out_pred,       // [NROWS]
    float* __restrict__ loss_out)       // [1]
{
    __shared__ float4 ldsP[Tt * 4 * 49];   // 34,496 B
    __shared__ float  sCnt[2 * Nn];
    __shared__ float  sScale[Tt];

    int blk = blockIdx.x;
    int b   = blk / BLKS_PER_B;
    int tid = threadIdx.x;

    // Phase A: per-(n,set) mask counts. pcnt index = 400*b + i for i=(n,ch,set).
    if (tid < 2 * Nn) sCnt[tid] = 0.0f;
    __syncthreads();
    for (int i = tid; i < 400; i += 128) {
        float v = pcnt[400 * b + i];
        int n   = i / 80;
        int set = i & 1;
        atomicAdd(&sCnt[2 * n + set], v);
    }
    __syncthreads();
    if (tid < Tt) {
        if (tid == 0) {
            float cO = (float)(KL * Nn);
            #pragma unroll
            for (int k = 0; k < 2 * Nn; ++k) cO -= sCnt[k];
            sScale[0] = 1.0f / (cO + EPS);
        } else {
            sScale[tid] = 1.0f / (sCnt[tid - 1] + EPS);
        }
    }
    __syncthreads();

    // Phase B: stage scaled prototypes into LDS. tag t=0 -> O = sum_n(All-B-I).
    const float4* bs = (const float4*)bnsum + (size_t)b * Nn * 3 * F4;  // [n][3][F4]
    for (int idx = tid; idx < Tt * F4; idx += 128) {
        int t  = idx / F4;
        int f4 = idx - t * F4;
        float4 val;
        if (t == 0) {
            float sx = 0, sy = 0, sz = 0, sw = 0;
            #pragma unroll
            for (int n = 0; n < Nn; ++n) {
                float4 A = bs[(n * 3 + 2) * F4 + f4];
                float4 Bv = bs[(n * 3 + 0) * F4 + f4];
                float4 Iv = bs[(n * 3 + 1) * F4 + f4];
                sx += A.x - Bv.x - Iv.x; sy += A.y - Bv.y - Iv.y;
                sz += A.z - Bv.z - Iv.z; sw += A.w - Bv.w - Iv.w;
            }
            val.x = sx; val.y = sy; val.z = sz; val.w = sw;
        } else {
            int n   = (t - 1) >> 1;
            int set = (t - 1) & 1;
            val = bs[(n * 3 + set) * F4 + f4];
        }
        float sc = sScale[t];
        val.x *= sc; val.y *= sc; val.z *= sc; val.w *= sc;
        int s = f4 / 48, j = f4 - 48 * s;
        ldsP[(t * 4 + s) * 49 + j] = val;
    }
    __syncthreads();

    int w    = tid >> 6;
    int lane = tid & 63;
    int p    = lane >> 2;
    int s    = lane & 3;

    size_t row0 = (size_t)blk * S3_ROWS + w * 32 + p * 2;
    const float4* q0 = (const float4*)(query + row0 * Ff) + s * 48;
    const float4* q1 = q0 + F4;

    float a0[Tt], a1[Tt];
    #pragma unroll
    for (int t = 0; t < Tt; ++t) { a0[t] = 0.0f; a1[t] = 0.0f; }

    const float4* pb = &ldsP[s * 49];
    #pragma unroll 2
    for (int j = 0; j < 48; ++j) {
        float4 u = q0[j];
        float4 v = q1[j];
        #pragma unroll
        for (int t = 0; t < Tt; ++t) {
            float4 pv = pb[t * (4 * 49) + j];
            float d0 = a0[t], d1 = a1[t];
            d0 = fmaf(u.x, pv.x, d0); d0 = fmaf(u.y, pv.y, d0);
            d0 = fmaf(u.z, pv.z, d0); d0 = fmaf(u.w, pv.w, d0);
            d1 = fmaf(v.x, pv.x, d1); d1 = fmaf(v.y, pv.y, d1);
            d1 = fmaf(v.z, pv.z, d1); d1 = fmaf(v.w, pv.w, d1);
            a0[t] = d0; a1[t] = d1;
        }
    }

    #pragma unroll
    for (int t = 0; t < Tt; ++t) {
        a0[t] += __shfl_xor(a0[t], 1, 64); a0[t] += __shfl_xor(a0[t], 2, 64);
        a1[t] += __shfl_xor(a1[t], 1, 64); a1[t] += __shfl_xor(a1[t], 2, 64);
    }

    float wloss = 0.0f;
    if (s == 0) {
        #pragma unroll
        for (int rr = 0; rr < 2; ++rr) {
            size_t grow = row0 + rr;
            float* a = rr ? a1 : a0;
            float m = a[0]; int bt = 0;
            #pragma unroll
            for (int t = 1; t < Tt; ++t) if (a[t] > m) { m = a[t]; bt = t; }  // first-max
            float sum = 0.0f;
            #pragma unroll
            for (int t = 0; t < Tt; ++t) sum += __expf(a[t] - m);
            int lab = label[grow];
            float labv = a[0];
            #pragma unroll
            for (int t = 1; t < Tt; ++t) labv = (lab == t) ? a[t] : labv;
            #pragma unroll
            for (int t = 0; t < Tt; ++t) out_logits[grow * Tt + t] = a[t];
            out_pred[grow] = (float)bt;
            wloss += (m + __logf(sum)) - labv;
        }
    }
    #pragma unroll
    for (int off = 32; off > 0; off >>= 1) wloss += __shfl_xor(wloss, off, 64);
    if (lane == 0) atomicAdd(loss_out, wloss * (1.0f / (float)NROWS));
}

// ---------------- Host launch ----------------
extern "C" void kernel_launch(void* const* d_in, const int* in_sizes, int n_in,
                              void* d_out, int out_size, void* d_ws, size_t ws_size,
                              hipStream_t stream) {
    const float* sup   = (const float*)d_in[0];
    const float* query = (const float*)d_in[1];
    const int*   Bm    = (const int*)d_in[2];
    const int*   Im    = (const int*)d_in[3];
    const int*   lab   = (const int*)d_in[4];

    // ws layout: part [1600][2304] | pcnt [1600][2] | bnsum [40][3][768]
    float* w     = (float*)d_ws;
    float* part  = w;
    float* pcnt  = part + (size_t)S1_NBLK * PART_STRIDE;   // +3,686,400
    float* bnsum = pcnt + 2 * S1_NBLK;                     // +3,200 (16B-aligned)

    float* loss_out   = (float*)d_out;
    float* out_logits = (float*)d_out + 1;
    float* out_pred   = (float*)d_out + 1 + (size_t)NROWS * Tt;

    stage1<<<S1_NBLK, 192, 0, stream>>>(sup, Bm, Im, part, pcnt);
    stage2<<<90, 256, 0, stream>>>(part, bnsum, loss_out);
    stage3<<<S3_NBLK, 128, 0, stream>>>(query, bnsum, pcnt, lab,
                                        out_logits, out_pred, loss_out);
}